// Round 12
// baseline (171.376 us; speedup 1.0000x reference)
//
#include <hip/hip_runtime.h>
#include <stdint.h>

#define S_LEN 2048
#define BATCH 2
#define DM 1024
#define NH 16
#define DH 64
#define MROWS 4096  // BATCH * S_LEN

typedef unsigned short u16;
typedef unsigned int u32;
typedef __attribute__((ext_vector_type(8))) short bf16x8;
typedef __attribute__((ext_vector_type(4))) float f32x4;
typedef __attribute__((ext_vector_type(2))) unsigned u32x2;

union pack8 { u32 w[4]; bf16x8 v8; };

__device__ inline u16 f2bf(float f) {
  union { float f; unsigned u; } v; v.f = f;
  unsigned u = v.u;
  unsigned r = u + 0x7fffu + ((u >> 16) & 1u);
  return (u16)(r >> 16);
}

__device__ inline u32 pkbf(float lo, float hi) {
  u32 r;
  asm("v_cvt_pk_bf16_f32 %0, %1, %2" : "=v"(r) : "v"(lo), "v"(hi));
  return r;
}

__device__ inline float bf2f(short s) {
  union { u32 u; float f; } c; c.u = ((u32)(u16)s) << 16;
  return c.f;
}

// ---------------- fp32 -> bf16 conversion for x, Wq, Wk, Wv, Wo ----------------
__global__ void convert_k(const float* __restrict__ x, const float* __restrict__ wq,
                          const float* __restrict__ wk, const float* __restrict__ wv,
                          const float* __restrict__ wo, u16* __restrict__ xb,
                          u16* __restrict__ wb) {
  int i = blockIdx.x * blockDim.x + threadIdx.x;
  const int total = (MROWS * DM + 4 * DM * DM) / 4;  // 2,097,152 float4 groups
  if (i >= total) return;
  int e = i * 4;
  const float* src;
  u16* dst;
  if (e < MROWS * DM) {
    src = x + e; dst = xb + e;
  } else {
    int j = e - MROWS * DM;
    int w = j >> 20;
    int o = j & ((1 << 20) - 1);
    src = (w == 0) ? wq + o : (w == 1) ? wk + o : (w == 2) ? wv + o : wo + o;
    dst = wb + j;
  }
  float4 v = *(const float4*)src;
  uint2 r;
  r.x = (unsigned)f2bf(v.x) | ((unsigned)f2bf(v.y) << 16);
  r.y = (unsigned)f2bf(v.z) | ((unsigned)f2bf(v.w) << 16);
  *(uint2*)dst = r;
}

// ---------------- RoPE cos/sin table [S][32]; also zero kmax[32] ----------------
__global__ void rope_k(float2* __restrict__ tab, float* __restrict__ kmax) {
  int i = blockIdx.x * blockDim.x + threadIdx.x;
  if (i < 32) kmax[i] = 0.f;
  if (i >= S_LEN * 32) return;
  int s = i >> 5, p = i & 31;
  float inv = expf(-(float)p * 0.28782313662425575f);  // ln(10000)/32
  float a = (float)s * inv;
  tab[i] = make_float2(cosf(a), sinf(a));
}

// ---------------- per-bh max row norm of K (for static softmax bound) ----------------
__global__ void knorm_k(const u16* __restrict__ K, float* __restrict__ kmax) {
  const int row = blockIdx.x * 256 + threadIdx.x;  // 65536 rows = B*H*S
  const int bh = row >> 11;
  const u16* p = K + (size_t)row * DH;
  float ss = 0.f;
#pragma unroll
  for (int i = 0; i < 8; i++) {
    bf16x8 v = *(const bf16x8*)(p + i * 8);
#pragma unroll
    for (int j = 0; j < 8; j++) { float f = bf2f(v[j]); ss += f * f; }
  }
  float kn = sqrtf(ss);
#pragma unroll
  for (int d = 1; d < 64; d <<= 1) kn = fmaxf(kn, __shfl_xor(kn, d));
  if ((threadIdx.x & 63) == 0)
    atomicMax((unsigned*)(kmax + bh), __float_as_uint(kn));
}

// ---------------- GEMM: C = A @ W^T + bias, fused epilogues ----------------
// mode 0: Q  -> rope, *0.125*log2e, bf16 [B,H,S,Dh]   (log2e folded so attn uses exp2)
// mode 1: K  -> rope, bf16 [B,H,S,Dh]
// mode 2: V  -> bf16 [B,H,Dh,S] with per-32 s-block permutation matching the
//               attn PV fragment (pos = ((j&15)>>2)*8 + (j>>4)*4 + (j&3))
// mode 3: O  -> fp32 [M, DM]
__launch_bounds__(256)
__global__ void gemm_k(const u16* __restrict__ A,
                       const u16* __restrict__ w0, const u16* __restrict__ w1,
                       const u16* __restrict__ w2,
                       const float* __restrict__ b0, const float* __restrict__ b1,
                       const float* __restrict__ b2,
                       const float2* __restrict__ rope,
                       void* __restrict__ o0, void* __restrict__ o1, void* __restrict__ o2,
                       int mode0) {
  const int mode = mode0 + (int)(blockIdx.x >> 8);
  const int tile = blockIdx.x & 255;
  const int mt = tile >> 3, nt = tile & 7;
  const int mbase = mt * 128, nbase = nt * 128;
  const u16* W = (mode == 1) ? w1 : (mode == 2) ? w2 : w0;
  const float* bias = (mode == 1) ? b1 : (mode == 2) ? b2 : b0;
  void* outp = (mode == 1) ? o1 : (mode == 2) ? o2 : o0;

  __shared__ u16 As[128 * 40];  // padded row stride 40 (2-way bank aliasing = free)
  __shared__ u16 Bs[128 * 40];

  const int t = threadIdx.x;
  const int lane = t & 63, wvi = t >> 6;
  const int lr = lane & 15, lg = lane >> 4;
  const int wm = (wvi >> 1) * 64, wn = (wvi & 1) * 64;

  f32x4 acc[4][4] = {};
  const int srow = t >> 2;        // 0..63
  const int scol = (t & 3) * 8;   // 0,8,16,24

  for (int kk = 0; kk < DM; kk += 32) {
    bf16x8 a0 = *(const bf16x8*)(A + (size_t)(mbase + srow) * DM + kk + scol);
    bf16x8 a1 = *(const bf16x8*)(A + (size_t)(mbase + 64 + srow) * DM + kk + scol);
    bf16x8 g0 = *(const bf16x8*)(W + (size_t)(nbase + srow) * DM + kk + scol);
    bf16x8 g1 = *(const bf16x8*)(W + (size_t)(nbase + 64 + srow) * DM + kk + scol);
    __syncthreads();
    *(bf16x8*)&As[srow * 40 + scol] = a0;
    *(bf16x8*)&As[(64 + srow) * 40 + scol] = a1;
    *(bf16x8*)&Bs[srow * 40 + scol] = g0;
    *(bf16x8*)&Bs[(64 + srow) * 40 + scol] = g1;
    __syncthreads();
    bf16x8 af[4], bfr[4];
#pragma unroll
    for (int mi = 0; mi < 4; mi++)
      af[mi] = *(const bf16x8*)&As[(wm + mi * 16 + lr) * 40 + lg * 8];
#pragma unroll
    for (int ni = 0; ni < 4; ni++)
      bfr[ni] = *(const bf16x8*)&Bs[(wn + ni * 16 + lr) * 40 + lg * 8];
#pragma unroll
    for (int mi = 0; mi < 4; mi++)
#pragma unroll
      for (int ni = 0; ni < 4; ni++)
        acc[mi][ni] = __builtin_amdgcn_mfma_f32_16x16x32_bf16(af[mi], bfr[ni], acc[mi][ni], 0, 0, 0);
  }

#pragma unroll
  for (int ni = 0; ni < 4; ni++) {
    const int col = nbase + wn + ni * 16 + lr;
    const float bv = bias[col];
#pragma unroll
    for (int mi = 0; mi < 4; mi++) {
      const int row0 = mbase + wm + mi * 16 + lg * 4;
      f32x4 v = acc[mi][ni];
#pragma unroll
      for (int r = 0; r < 4; r++) {
        float val = v[r] + bv;
        const int row = row0 + r;
        if (mode <= 1) {
          float nb = __shfl_xor(val, 1);
          const int d = col & 63, p = d >> 1, s = row & (S_LEN - 1);
          float2 cs = rope[s * 32 + p];
          float ov = (d & 1) ? (nb * cs.y + val * cs.x) : (val * cs.x - nb * cs.y);
          if (mode == 0) ov *= 0.18033688011112042f;  // 1/sqrt(Dh) * log2(e)
          const int b = row >> 11, h = col >> 6;
          ((u16*)outp)[((size_t)(b * NH + h) * S_LEN + s) * DH + d] = f2bf(ov);
        } else if (mode == 2) {
          const int b = row >> 11, h = col >> 6, d = col & 63, s = row & (S_LEN - 1);
          const int j = s & 31;
          const int pos = (s & ~31) + (((j & 15) >> 2) << 3) + ((j >> 4) << 2) + (j & 3);
          ((u16*)outp)[((size_t)(b * NH + h) * DH + d) * S_LEN + pos] = f2bf(val);
        } else {
          ((float*)outp)[(size_t)row * DM + col] = val;
        }
      }
    }
  }
}

// ---- static-bound softmax + PV for one (chain, q-group): accumulate into o[4] ----
__device__ __forceinline__ void sm_pv(const float a[8], float m, float& l,
                                      bf16x8 v0, bf16x8 v1, bf16x8 v2, bf16x8 v3,
                                      f32x4* o) {
  float p[8];
#pragma unroll
  for (int r = 0; r < 8; r++) p[r] = __builtin_amdgcn_exp2f(a[r] - m);
  l += ((p[0] + p[1]) + (p[2] + p[3])) + ((p[4] + p[5]) + (p[6] + p[7]));
  pack8 pu;
  pu.w[0] = pkbf(p[0], p[1]);
  pu.w[1] = pkbf(p[2], p[3]);
  pu.w[2] = pkbf(p[4], p[5]);
  pu.w[3] = pkbf(p[6], p[7]);
  o[0] = __builtin_amdgcn_mfma_f32_16x16x32_bf16(v0, pu.v8, o[0], 0, 0, 0);
  o[1] = __builtin_amdgcn_mfma_f32_16x16x32_bf16(v1, pu.v8, o[1], 0, 0, 0);
  o[2] = __builtin_amdgcn_mfma_f32_16x16x32_bf16(v2, pu.v8, o[2], 0, 0, 0);
  o[3] = __builtin_amdgcn_mfma_f32_16x16x32_bf16(v3, pu.v8, o[3], 0, 0, 0);
}

// ---------------- causal flash attention: QBLK=32 + dual-chain kv-split + XCD pin ----
// R11 structure (proven correct) + XCD-aware block mapping: workgroup lands on
// XCD (blockIdx%8), so map b = (tile*4 + (bh&3))*8 + (bh>>2) -> all 64 tiles of a
// 4-bh group run on ONE XCD. Per-XCD hot K+V = 4 bh x 512 KB = 2 MB < 4 MB L2 ->
// K/V re-reads served from L2 (~34.5 TB/s agg) instead of L3 (~7.3 TB/s, the
// measured R7/R10/R11 traffic wall).
__launch_bounds__(64)
__global__ void attn_k(const u16* __restrict__ Q, const u16* __restrict__ K,
                       const u16* __restrict__ Vt, u16* __restrict__ Oo,
                       const float* __restrict__ kmax) {
  const int bh = ((blockIdx.x & 7) << 2) | ((blockIdx.x >> 3) & 3);  // XCD-pinned
  const int tile = 63 - (blockIdx.x >> 5);  // longest first (causal load balance)
  const int qbase = tile * 32;
  const int lane = threadIdx.x;
  const int lr = lane & 15, lg = lane >> 4;

  const size_t qoff = ((size_t)bh * S_LEN + qbase + lr) * DH + lg * 8;
  const bf16x8 qA0 = *(const bf16x8*)(Q + qoff);
  const bf16x8 qA1 = *(const bf16x8*)(Q + qoff + 32);
  const bf16x8 qB0 = *(const bf16x8*)(Q + qoff + 16 * DH);
  const bf16x8 qB1 = *(const bf16x8*)(Q + qoff + 16 * DH + 32);

  // ---- static softmax bounds (prologue, off the hot loop) ----
  float ssA = 0.f, ssB = 0.f;
#pragma unroll
  for (int j = 0; j < 8; j++) {
    float a0 = bf2f(qA0[j]), a1 = bf2f(qA1[j]);
    float b0 = bf2f(qB0[j]), b1 = bf2f(qB1[j]);
    ssA += a0 * a0 + a1 * a1;
    ssB += b0 * b0 + b1 * b1;
  }
  ssA += __shfl_xor(ssA, 16); ssA += __shfl_xor(ssA, 32);
  ssB += __shfl_xor(ssB, 16); ssB += __shfl_xor(ssB, 32);
  const float kmx = kmax[bh];
  const float mA = sqrtf(ssA) * kmx;
  const float mB = sqrtf(ssB) * kmx;

  f32x4 oA[4] = {}, oB[4] = {};
  float lA = 0.f, lB = 0.f;
  const f32x4 zero = {};
  const int nst = tile + 1;                 // 32-wide kv steps; last one masked
  const int half = nst >> 1;                // chain0: [0,half)  chain1: [half,nst)
  const int jn = (nst - 1) >> 1;            // joint iterations (both chains)
  const int solo = half - jn;               // 0 or 1 extra chain0 step

  const u16* Kp0 = K + ((size_t)bh * S_LEN + lr) * DH + lg * 8;
  const u16* Kp1 = K + ((size_t)bh * S_LEN + half * 32 + lr) * DH + lg * 8;
  const u16* Vp0 = Vt + ((size_t)bh * DH + lr) * S_LEN + lg * 8;
  const u16* Vp1 = Vp0 + half * 32;

  bf16x8 kc00 = *(const bf16x8*)(Kp0);
  bf16x8 kc01 = *(const bf16x8*)(Kp0 + 32);
  bf16x8 kc02 = *(const bf16x8*)(Kp0 + 16 * DH);
  bf16x8 kc03 = *(const bf16x8*)(Kp0 + 16 * DH + 32);
  bf16x8 kc10 = *(const bf16x8*)(Kp1);
  bf16x8 kc11 = *(const bf16x8*)(Kp1 + 32);
  bf16x8 kc12 = *(const bf16x8*)(Kp1 + 16 * DH);
  bf16x8 kc13 = *(const bf16x8*)(Kp1 + 16 * DH + 32);

  // ---- joint hot loop: both chains x both q-groups, branch-free single BB ----
  for (int it = 0; it < jn; ++it) {
    bf16x8 va0 = *(const bf16x8*)(Vp0);
    bf16x8 va1 = *(const bf16x8*)(Vp0 + 16 * S_LEN);
    bf16x8 va2 = *(const bf16x8*)(Vp0 + 32 * S_LEN);
    bf16x8 va3 = *(const bf16x8*)(Vp0 + 48 * S_LEN);
    bf16x8 vb0 = *(const bf16x8*)(Vp1);
    bf16x8 vb1 = *(const bf16x8*)(Vp1 + 16 * S_LEN);
    bf16x8 vb2 = *(const bf16x8*)(Vp1 + 32 * S_LEN);
    bf16x8 vb3 = *(const bf16x8*)(Vp1 + 48 * S_LEN);
    Vp0 += 32; Vp1 += 32;

    // chain0 scores (both q-groups share kc0*)
    f32x4 sa0A = __builtin_amdgcn_mfma_f32_16x16x32_bf16(kc00, qA0, zero, 0, 0, 0);
    sa0A = __builtin_amdgcn_mfma_f32_16x16x32_bf16(kc01, qA1, sa0A, 0, 0, 0);
    f32x4 sa1A = __builtin_amdgcn_mfma_f32_16x16x32_bf16(kc02, qA0, zero, 0, 0, 0);
    sa1A = __builtin_amdgcn_mfma_f32_16x16x32_bf16(kc03, qA1, sa1A, 0, 0, 0);
    f32x4 sa0B = __builtin_amdgcn_mfma_f32_16x16x32_bf16(kc00, qB0, zero, 0, 0, 0);
    sa0B = __builtin_amdgcn_mfma_f32_16x16x32_bf16(kc01, qB1, sa0B, 0, 0, 0);
    f32x4 sa1B = __builtin_amdgcn_mfma_f32_16x16x32_bf16(kc02, qB0, zero, 0, 0, 0);
    sa1B = __builtin_amdgcn_mfma_f32_16x16x32_bf16(kc03, qB1, sa1B, 0, 0, 0);
    // chain1 scores (share kc1*)
    f32x4 sb0A = __builtin_amdgcn_mfma_f32_16x16x32_bf16(kc10, qA0, zero, 0, 0, 0);
    sb0A = __builtin_amdgcn_mfma_f32_16x16x32_bf16(kc11, qA1, sb0A, 0, 0, 0);
    f32x4 sb1A = __builtin_amdgcn_mfma_f32_16x16x32_bf16(kc12, qA0, zero, 0, 0, 0);
    sb1A = __builtin_amdgcn_mfma_f32_16x16x32_bf16(kc13, qA1, sb1A, 0, 0, 0);
    f32x4 sb0B = __builtin_amdgcn_mfma_f32_16x16x32_bf16(kc10, qB0, zero, 0, 0, 0);
    sb0B = __builtin_amdgcn_mfma_f32_16x16x32_bf16(kc11, qB1, sb0B, 0, 0, 0);
    f32x4 sb1B = __builtin_amdgcn_mfma_f32_16x16x32_bf16(kc12, qB0, zero, 0, 0, 0);
    sb1B = __builtin_amdgcn_mfma_f32_16x16x32_bf16(kc13, qB1, sb1B, 0, 0, 0);

    // prefetch next step's K for both chains (chain1's last prefetch = masked step)
    Kp0 += 32 * DH;
    kc00 = *(const bf16x8*)(Kp0);
    kc01 = *(const bf16x8*)(Kp0 + 32);
    kc02 = *(const bf16x8*)(Kp0 + 16 * DH);
    kc03 = *(const bf16x8*)(Kp0 + 16 * DH + 32);
    Kp1 += 32 * DH;
    kc10 = *(const bf16x8*)(Kp1);
    kc11 = *(const bf16x8*)(Kp1 + 32);
    kc12 = *(const bf16x8*)(Kp1 + 16 * DH);
    kc13 = *(const bf16x8*)(Kp1 + 16 * DH + 32);

    float a0A[8], a0B[8], a1A[8], a1B[8];
#pragma unroll
    for (int r = 0; r < 4; r++) {
      a0A[r] = sa0A[r]; a0A[4 + r] = sa1A[r];
      a0B[r] = sa0B[r]; a0B[4 + r] = sa1B[r];
      a1A[r] = sb0A[r]; a1A[4 + r] = sb1A[r];
      a1B[r] = sb0B[r]; a1B[4 + r] = sb1B[r];
    }
    sm_pv(a0A, mA, lA, va0, va1, va2, va3, oA);
    sm_pv(a0B, mB, lB, va0, va1, va2, va3, oB);
    sm_pv(a1A, mA, lA, vb0, vb1, vb2, vb3, oA);
    sm_pv(a1B, mB, lB, vb0, vb1, vb2, vb3, oB);
  }

  // ---- optional solo chain0 step (nst even): kc0 holds step jn = half-1 ----
  if (solo) {
    bf16x8 va0 = *(const bf16x8*)(Vp0);
    bf16x8 va1 = *(const bf16x8*)(Vp0 + 16 * S_LEN);
    bf16x8 va2 = *(const bf16x8*)(Vp0 + 32 * S_LEN);
    bf16x8 va3 = *(const bf16x8*)(Vp0 + 48 * S_LEN);

    f32x4 s0A = __builtin_amdgcn_mfma_f32_16x16x32_bf16(kc00, qA0, zero, 0, 0, 0);
    s0A = __builtin_amdgcn_mfma_f32_16x16x32_bf16(kc01, qA1, s0A, 0, 0, 0);
    f32x4 s1A = __builtin_amdgcn_mfma_f32_16x16x32_bf16(kc02, qA0, zero, 0, 0, 0);
    s1A = __builtin_amdgcn_mfma_f32_16x16x32_bf16(kc03, qA1, s1A, 0, 0, 0);
    f32x4 s0B = __builtin_amdgcn_mfma_f32_16x16x32_bf16(kc00, qB0, zero, 0, 0, 0);
    s0B = __builtin_amdgcn_mfma_f32_16x16x32_bf16(kc01, qB1, s0B, 0, 0, 0);
    f32x4 s1B = __builtin_amdgcn_mfma_f32_16x16x32_bf16(kc02, qB0, zero, 0, 0, 0);
    s1B = __builtin_amdgcn_mfma_f32_16x16x32_bf16(kc03, qB1, s1B, 0, 0, 0);

    float aA[8], aB[8];
#pragma unroll
    for (int r = 0; r < 4; r++) {
      aA[r] = s0A[r]; aA[4 + r] = s1A[r];
      aB[r] = s0B[r]; aB[4 + r] = s1B[r];
    }
    sm_pv(aA, mA, lA, va0, va1, va2, va3, oA);
    sm_pv(aB, mB, lB, va0, va1, va2, va3, oB);
  }

  // ---- chain1 masked diagonal step: kc1 holds step nst-1 (both parities) ----
  {
    bf16x8 vb0 = *(const bf16x8*)(Vp1);
    bf16x8 vb1 = *(const bf16x8*)(Vp1 + 16 * S_LEN);
    bf16x8 vb2 = *(const bf16x8*)(Vp1 + 32 * S_LEN);
    bf16x8 vb3 = *(const bf16x8*)(Vp1 + 48 * S_LEN);

    f32x4 s0A = __builtin_amdgcn_mfma_f32_16x16x32_bf16(kc10, qA0, zero, 0, 0, 0);
    s0A = __builtin_amdgcn_mfma_f32_16x16x32_bf16(kc11, qA1, s0A, 0, 0, 0);
    f32x4 s1A = __builtin_amdgcn_mfma_f32_16x16x32_bf16(kc12, qA0, zero, 0, 0, 0);
    s1A = __builtin_amdgcn_mfma_f32_16x16x32_bf16(kc13, qA1, s1A, 0, 0, 0);
    f32x4 s0B = __builtin_amdgcn_mfma_f32_16x16x32_bf16(kc10, qB0, zero, 0, 0, 0);
    s0B = __builtin_amdgcn_mfma_f32_16x16x32_bf16(kc11, qB1, s0B, 0, 0, 0);
    f32x4 s1B = __builtin_amdgcn_mfma_f32_16x16x32_bf16(kc12, qB0, zero, 0, 0, 0);
    s1B = __builtin_amdgcn_mfma_f32_16x16x32_bf16(kc13, qB1, s1B, 0, 0, 0);

    // A group: q = qbase+lr; valid iff kv row qbase+lg*4+r (+16) <= q
    const int qrelA = lr - lg * 4;
    const int qrelB = qrelA + 16;
    float aA[8], aB[8];
#pragma unroll
    for (int r = 0; r < 4; r++) {
      aA[r]     = (r <= qrelA)      ? s0A[r] : -__builtin_inff();
      aA[4 + r] = (r + 16 <= qrelA) ? s1A[r] : -__builtin_inff();  // never valid
      aB[r]     = s0B[r];                                          // always valid
      aB[4 + r] = (r + 16 <= qrelB) ? s1B[r] : -__builtin_inff();
    }
    sm_pv(aA, mA, lA, vb0, vb1, vb2, vb3, oA);
    sm_pv(aB, mB, lB, vb0, vb1, vb2, vb3, oB);
  }

  // ---- epilogue: lane holds q=lr, d = dt*16 + lg*4 + r ----
  lA += __shfl_xor(lA, 16); lA += __shfl_xor(lA, 32);
  lB += __shfl_xor(lB, 16); lB += __shfl_xor(lB, 32);
  const float rlA = __builtin_amdgcn_rcpf(lA);
  const float rlB = __builtin_amdgcn_rcpf(lB);

  const int b = bh >> 4, h = bh & 15;
  const size_t obaseA = ((size_t)b * S_LEN + qbase + lr) * DM + h * DH;
  const size_t obaseB = obaseA + (size_t)16 * DM;
#pragma unroll
  for (int dt = 0; dt < 4; dt++) {
    u32x2 pkA, pkB;
    pkA.x = pkbf(oA[dt][0] * rlA, oA[dt][1] * rlA);
    pkA.y = pkbf(oA[dt][2] * rlA, oA[dt][3] * rlA);
    pkB.x = pkbf(oB[dt][0] * rlB, oB[dt][1] * rlB);
    pkB.y = pkbf(oB[dt][2] * rlB, oB[dt][3] * rlB);
    *(u32x2*)(Oo + obaseA + dt * 16 + lg * 4) = pkA;
    *(u32x2*)(Oo + obaseB + dt * 16 + lg * 4) = pkB;
  }
}

// ---------------- host launcher ----------------
extern "C" void kernel_launch(void* const* d_in, const int* in_sizes, int n_in,
                              void* d_out, int out_size, void* d_ws, size_t ws_size,
                              hipStream_t stream) {
  const float* x  = (const float*)d_in[0];
  const float* Wq = (const float*)d_in[1];
  const float* bq = (const float*)d_in[2];
  const float* Wk = (const float*)d_in[3];
  const float* bk = (const float*)d_in[4];
  const float* Wv = (const float*)d_in[5];
  const float* bv = (const float*)d_in[6];
  const float* Wo = (const float*)d_in[7];
  const float* bo = (const float*)d_in[8];

  char* ws = (char*)d_ws;
  u16* xb    = (u16*)(ws);                 // 8 MB  [4096,1024] bf16
  u16* wb    = (u16*)(ws + (8u << 20));    // 8 MB  Wq,Wk,Wv,Wo bf16
  u16* Qb    = (u16*)(ws + (16u << 20));   // 8 MB  [B,H,S,Dh]
  u16* Kb    = (u16*)(ws + (24u << 20));   // 8 MB  [B,H,S,Dh]
  u16* Vtb   = (u16*)(ws + (32u << 20));   // 8 MB  [B,H,Dh,S] (s-permuted)
  u16* AOb   = (u16*)(ws + (40u << 20));   // 8 MB  [B*S, DM]
  float2* rt = (float2*)(ws + (48u << 20));            // 512 KB rope table
  float* kmx = (float*)(ws + (48u << 20) + (512u << 10));  // 128 B kmax[32]

  convert_k<<<8192, 256, 0, stream>>>(x, Wq, Wk, Wv, Wo, xb, wb);
  rope_k<<<256, 256, 0, stream>>>(rt, kmx);
  gemm_k<<<768, 256, 0, stream>>>(xb, wb, wb + (1u << 20), wb + (2u << 20),
                                  bq, bk, bv, rt, Qb, Kb, Vtb, 0);
  knorm_k<<<256, 256, 0, stream>>>(Kb, kmx);
  attn_k<<<2048, 64, 0, stream>>>(Qb, Kb, Vtb, AOb, kmx);
  gemm_k<<<256, 256, 0, stream>>>(AOb, wb + (3u << 20), wb + (3u << 20), wb + (3u << 20),
                                  bo, bo, bo, rt, d_out, d_out, d_out, 3);
}

// Round 13
// 171.161 us; speedup vs baseline: 1.0013x; 1.0013x over previous
//
#include <hip/hip_runtime.h>
#include <stdint.h>

#define S_LEN 2048
#define BATCH 2
#define DM 1024
#define NH 16
#define DH 64
#define MROWS 4096  // BATCH * S_LEN

typedef unsigned short u16;
typedef unsigned int u32;
typedef __attribute__((ext_vector_type(8))) short bf16x8;
typedef __attribute__((ext_vector_type(4))) float f32x4;
typedef __attribute__((ext_vector_type(2))) unsigned u32x2;

union pack8 { u32 w[4]; bf16x8 v8; };

__device__ inline u16 f2bf(float f) {
  union { float f; unsigned u; } v; v.f = f;
  unsigned u = v.u;
  unsigned r = u + 0x7fffu + ((u >> 16) & 1u);
  return (u16)(r >> 16);
}

__device__ inline u32 pkbf(float lo, float hi) {
  u32 r;
  asm("v_cvt_pk_bf16_f32 %0, %1, %2" : "=v"(r) : "v"(lo), "v"(hi));
  return r;
}

__device__ inline float bf2f(short s) {
  union { u32 u; float f; } c; c.u = ((u32)(u16)s) << 16;
  return c.f;
}

// ---------------- fp32 -> bf16 conversion for x, Wq, Wk, Wv, Wo ----------------
__global__ void convert_k(const float* __restrict__ x, const float* __restrict__ wq,
                          const float* __restrict__ wk, const float* __restrict__ wv,
                          const float* __restrict__ wo, u16* __restrict__ xb,
                          u16* __restrict__ wb) {
  int i = blockIdx.x * blockDim.x + threadIdx.x;
  const int total = (MROWS * DM + 4 * DM * DM) / 4;  // 2,097,152 float4 groups
  if (i >= total) return;
  int e = i * 4;
  const float* src;
  u16* dst;
  if (e < MROWS * DM) {
    src = x + e; dst = xb + e;
  } else {
    int j = e - MROWS * DM;
    int w = j >> 20;
    int o = j & ((1 << 20) - 1);
    src = (w == 0) ? wq + o : (w == 1) ? wk + o : (w == 2) ? wv + o : wo + o;
    dst = wb + j;
  }
  float4 v = *(const float4*)src;
  uint2 r;
  r.x = (unsigned)f2bf(v.x) | ((unsigned)f2bf(v.y) << 16);
  r.y = (unsigned)f2bf(v.z) | ((unsigned)f2bf(v.w) << 16);
  *(uint2*)dst = r;
}

// ---------------- RoPE cos/sin table [S][32]; also zero kmax[32] ----------------
__global__ void rope_k(float2* __restrict__ tab, float* __restrict__ kmax) {
  int i = blockIdx.x * blockDim.x + threadIdx.x;
  if (i < 32) kmax[i] = 0.f;
  if (i >= S_LEN * 32) return;
  int s = i >> 5, p = i & 31;
  float inv = expf(-(float)p * 0.28782313662425575f);  // ln(10000)/32
  float a = (float)s * inv;
  tab[i] = make_float2(cosf(a), sinf(a));
}

// ---------------- per-bh max row norm of K (for static softmax bound) ----------------
__global__ void knorm_k(const u16* __restrict__ K, float* __restrict__ kmax) {
  const int row = blockIdx.x * 256 + threadIdx.x;  // 65536 rows = B*H*S
  const int bh = row >> 11;
  const u16* p = K + (size_t)row * DH;
  float ss = 0.f;
#pragma unroll
  for (int i = 0; i < 8; i++) {
    bf16x8 v = *(const bf16x8*)(p + i * 8);
#pragma unroll
    for (int j = 0; j < 8; j++) { float f = bf2f(v[j]); ss += f * f; }
  }
  float kn = sqrtf(ss);
#pragma unroll
  for (int d = 1; d < 64; d <<= 1) kn = fmaxf(kn, __shfl_xor(kn, d));
  if ((threadIdx.x & 63) == 0)
    atomicMax((unsigned*)(kmax + bh), __float_as_uint(kn));
}

// ---------------- GEMM: C = A @ W^T + bias, fused epilogues ----------------
// mode 0: Q  -> rope, *0.125*log2e, bf16 [B,H,S,Dh]   (log2e folded so attn uses exp2)
// mode 1: K  -> rope, bf16 [B,H,S,Dh]
// mode 2: V  -> bf16 [B,H,Dh,S] with per-32 s-block permutation matching the
//               attn PV fragment (pos = ((j&15)>>2)*8 + (j>>4)*4 + (j&3))
// mode 3: O  -> fp32 [M, DM]
__launch_bounds__(256)
__global__ void gemm_k(const u16* __restrict__ A,
                       const u16* __restrict__ w0, const u16* __restrict__ w1,
                       const u16* __restrict__ w2,
                       const float* __restrict__ b0, const float* __restrict__ b1,
                       const float* __restrict__ b2,
                       const float2* __restrict__ rope,
                       void* __restrict__ o0, void* __restrict__ o1, void* __restrict__ o2,
                       int mode0) {
  const int mode = mode0 + (int)(blockIdx.x >> 8);
  const int tile = blockIdx.x & 255;
  const int mt = tile >> 3, nt = tile & 7;
  const int mbase = mt * 128, nbase = nt * 128;
  const u16* W = (mode == 1) ? w1 : (mode == 2) ? w2 : w0;
  const float* bias = (mode == 1) ? b1 : (mode == 2) ? b2 : b0;
  void* outp = (mode == 1) ? o1 : (mode == 2) ? o2 : o0;

  __shared__ u16 As[128 * 40];  // padded row stride 40 (2-way bank aliasing = free)
  __shared__ u16 Bs[128 * 40];

  const int t = threadIdx.x;
  const int lane = t & 63, wvi = t >> 6;
  const int lr = lane & 15, lg = lane >> 4;
  const int wm = (wvi >> 1) * 64, wn = (wvi & 1) * 64;

  f32x4 acc[4][4] = {};
  const int srow = t >> 2;        // 0..63
  const int scol = (t & 3) * 8;   // 0,8,16,24

  for (int kk = 0; kk < DM; kk += 32) {
    bf16x8 a0 = *(const bf16x8*)(A + (size_t)(mbase + srow) * DM + kk + scol);
    bf16x8 a1 = *(const bf16x8*)(A + (size_t)(mbase + 64 + srow) * DM + kk + scol);
    bf16x8 g0 = *(const bf16x8*)(W + (size_t)(nbase + srow) * DM + kk + scol);
    bf16x8 g1 = *(const bf16x8*)(W + (size_t)(nbase + 64 + srow) * DM + kk + scol);
    __syncthreads();
    *(bf16x8*)&As[srow * 40 + scol] = a0;
    *(bf16x8*)&As[(64 + srow) * 40 + scol] = a1;
    *(bf16x8*)&Bs[srow * 40 + scol] = g0;
    *(bf16x8*)&Bs[(64 + srow) * 40 + scol] = g1;
    __syncthreads();
    bf16x8 af[4], bfr[4];
#pragma unroll
    for (int mi = 0; mi < 4; mi++)
      af[mi] = *(const bf16x8*)&As[(wm + mi * 16 + lr) * 40 + lg * 8];
#pragma unroll
    for (int ni = 0; ni < 4; ni++)
      bfr[ni] = *(const bf16x8*)&Bs[(wn + ni * 16 + lr) * 40 + lg * 8];
#pragma unroll
    for (int mi = 0; mi < 4; mi++)
#pragma unroll
      for (int ni = 0; ni < 4; ni++)
        acc[mi][ni] = __builtin_amdgcn_mfma_f32_16x16x32_bf16(af[mi], bfr[ni], acc[mi][ni], 0, 0, 0);
  }

#pragma unroll
  for (int ni = 0; ni < 4; ni++) {
    const int col = nbase + wn + ni * 16 + lr;
    const float bv = bias[col];
#pragma unroll
    for (int mi = 0; mi < 4; mi++) {
      const int row0 = mbase + wm + mi * 16 + lg * 4;
      f32x4 v = acc[mi][ni];
#pragma unroll
      for (int r = 0; r < 4; r++) {
        float val = v[r] + bv;
        const int row = row0 + r;
        if (mode <= 1) {
          float nb = __shfl_xor(val, 1);
          const int d = col & 63, p = d >> 1, s = row & (S_LEN - 1);
          float2 cs = rope[s * 32 + p];
          float ov = (d & 1) ? (nb * cs.y + val * cs.x) : (val * cs.x - nb * cs.y);
          if (mode == 0) ov *= 0.18033688011112042f;  // 1/sqrt(Dh) * log2(e)
          const int b = row >> 11, h = col >> 6;
          ((u16*)outp)[((size_t)(b * NH + h) * S_LEN + s) * DH + d] = f2bf(ov);
        } else if (mode == 2) {
          const int b = row >> 11, h = col >> 6, d = col & 63, s = row & (S_LEN - 1);
          const int j = s & 31;
          const int pos = (s & ~31) + (((j & 15) >> 2) << 3) + ((j >> 4) << 2) + (j & 3);
          ((u16*)outp)[((size_t)(b * NH + h) * DH + d) * S_LEN + pos] = f2bf(val);
        } else {
          ((float*)outp)[(size_t)row * DM + col] = val;
        }
      }
    }
  }
}

// ---- static-bound softmax + PV for one (chain, q-group): accumulate into o[4] ----
__device__ __forceinline__ void sm_pv(const float a[8], float m, float& l,
                                      bf16x8 v0, bf16x8 v1, bf16x8 v2, bf16x8 v3,
                                      f32x4* o) {
  float p[8];
#pragma unroll
  for (int r = 0; r < 8; r++) p[r] = __builtin_amdgcn_exp2f(a[r] - m);
  l += ((p[0] + p[1]) + (p[2] + p[3])) + ((p[4] + p[5]) + (p[6] + p[7]));
  pack8 pu;
  pu.w[0] = pkbf(p[0], p[1]);
  pu.w[1] = pkbf(p[2], p[3]);
  pu.w[2] = pkbf(p[4], p[5]);
  pu.w[3] = pkbf(p[6], p[7]);
  o[0] = __builtin_amdgcn_mfma_f32_16x16x32_bf16(v0, pu.v8, o[0], 0, 0, 0);
  o[1] = __builtin_amdgcn_mfma_f32_16x16x32_bf16(v1, pu.v8, o[1], 0, 0, 0);
  o[2] = __builtin_amdgcn_mfma_f32_16x16x32_bf16(v2, pu.v8, o[2], 0, 0, 0);
  o[3] = __builtin_amdgcn_mfma_f32_16x16x32_bf16(v3, pu.v8, o[3], 0, 0, 0);
}

// ---------------- causal flash attention: QBLK=32 + dual-chain kv-split + XCD pin ----
// R12 structure, but __launch_bounds__(64, 1): grid gives only 2 waves/SIMD, so
// let the allocator use up to 256 VGPRs. At the default budget (108 VGPR) the
// live set (q 32 + o 32 + K cur 32 + V cur 32 + K next 32 + temps) forced the
// compiler to recycle load-destination regs with s_waitcnt between batches ->
// the 16 loads/iter serialized at ~170 cyc each (= the measured 2.7k cyc/iter).
// With a full budget all loads stay in flight and the 1-step prefetch works.
__launch_bounds__(64, 1)
__global__ void attn_k(const u16* __restrict__ Q, const u16* __restrict__ K,
                       const u16* __restrict__ Vt, u16* __restrict__ Oo,
                       const float* __restrict__ kmax) {
  const int bh = ((blockIdx.x & 7) << 2) | ((blockIdx.x >> 3) & 3);  // XCD-pinned
  const int tile = 63 - (blockIdx.x >> 5);  // longest first (causal load balance)
  const int qbase = tile * 32;
  const int lane = threadIdx.x;
  const int lr = lane & 15, lg = lane >> 4;

  const size_t qoff = ((size_t)bh * S_LEN + qbase + lr) * DH + lg * 8;
  const bf16x8 qA0 = *(const bf16x8*)(Q + qoff);
  const bf16x8 qA1 = *(const bf16x8*)(Q + qoff + 32);
  const bf16x8 qB0 = *(const bf16x8*)(Q + qoff + 16 * DH);
  const bf16x8 qB1 = *(const bf16x8*)(Q + qoff + 16 * DH + 32);

  // ---- static softmax bounds (prologue, off the hot loop) ----
  float ssA = 0.f, ssB = 0.f;
#pragma unroll
  for (int j = 0; j < 8; j++) {
    float a0 = bf2f(qA0[j]), a1 = bf2f(qA1[j]);
    float b0 = bf2f(qB0[j]), b1 = bf2f(qB1[j]);
    ssA += a0 * a0 + a1 * a1;
    ssB += b0 * b0 + b1 * b1;
  }
  ssA += __shfl_xor(ssA, 16); ssA += __shfl_xor(ssA, 32);
  ssB += __shfl_xor(ssB, 16); ssB += __shfl_xor(ssB, 32);
  const float kmx = kmax[bh];
  const float mA = sqrtf(ssA) * kmx;
  const float mB = sqrtf(ssB) * kmx;

  f32x4 oA[4] = {}, oB[4] = {};
  float lA = 0.f, lB = 0.f;
  const f32x4 zero = {};
  const int nst = tile + 1;                 // 32-wide kv steps; last one masked
  const int half = nst >> 1;                // chain0: [0,half)  chain1: [half,nst)
  const int jn = (nst - 1) >> 1;            // joint iterations (both chains)
  const int solo = half - jn;               // 0 or 1 extra chain0 step

  const u16* Kp0 = K + ((size_t)bh * S_LEN + lr) * DH + lg * 8;
  const u16* Kp1 = K + ((size_t)bh * S_LEN + half * 32 + lr) * DH + lg * 8;
  const u16* Vp0 = Vt + ((size_t)bh * DH + lr) * S_LEN + lg * 8;
  const u16* Vp1 = Vp0 + half * 32;

  bf16x8 kc00 = *(const bf16x8*)(Kp0);
  bf16x8 kc01 = *(const bf16x8*)(Kp0 + 32);
  bf16x8 kc02 = *(const bf16x8*)(Kp0 + 16 * DH);
  bf16x8 kc03 = *(const bf16x8*)(Kp0 + 16 * DH + 32);
  bf16x8 kc10 = *(const bf16x8*)(Kp1);
  bf16x8 kc11 = *(const bf16x8*)(Kp1 + 32);
  bf16x8 kc12 = *(const bf16x8*)(Kp1 + 16 * DH);
  bf16x8 kc13 = *(const bf16x8*)(Kp1 + 16 * DH + 32);

  // ---- joint hot loop: both chains x both q-groups, branch-free single BB ----
  for (int it = 0; it < jn; ++it) {
    bf16x8 va0 = *(const bf16x8*)(Vp0);
    bf16x8 va1 = *(const bf16x8*)(Vp0 + 16 * S_LEN);
    bf16x8 va2 = *(const bf16x8*)(Vp0 + 32 * S_LEN);
    bf16x8 va3 = *(const bf16x8*)(Vp0 + 48 * S_LEN);
    bf16x8 vb0 = *(const bf16x8*)(Vp1);
    bf16x8 vb1 = *(const bf16x8*)(Vp1 + 16 * S_LEN);
    bf16x8 vb2 = *(const bf16x8*)(Vp1 + 32 * S_LEN);
    bf16x8 vb3 = *(const bf16x8*)(Vp1 + 48 * S_LEN);
    Vp0 += 32; Vp1 += 32;

    // chain0 scores (both q-groups share kc0*)
    f32x4 sa0A = __builtin_amdgcn_mfma_f32_16x16x32_bf16(kc00, qA0, zero, 0, 0, 0);
    sa0A = __builtin_amdgcn_mfma_f32_16x16x32_bf16(kc01, qA1, sa0A, 0, 0, 0);
    f32x4 sa1A = __builtin_amdgcn_mfma_f32_16x16x32_bf16(kc02, qA0, zero, 0, 0, 0);
    sa1A = __builtin_amdgcn_mfma_f32_16x16x32_bf16(kc03, qA1, sa1A, 0, 0, 0);
    f32x4 sa0B = __builtin_amdgcn_mfma_f32_16x16x32_bf16(kc00, qB0, zero, 0, 0, 0);
    sa0B = __builtin_amdgcn_mfma_f32_16x16x32_bf16(kc01, qB1, sa0B, 0, 0, 0);
    f32x4 sa1B = __builtin_amdgcn_mfma_f32_16x16x32_bf16(kc02, qB0, zero, 0, 0, 0);
    sa1B = __builtin_amdgcn_mfma_f32_16x16x32_bf16(kc03, qB1, sa1B, 0, 0, 0);
    // chain1 scores (share kc1*)
    f32x4 sb0A = __builtin_amdgcn_mfma_f32_16x16x32_bf16(kc10, qA0, zero, 0, 0, 0);
    sb0A = __builtin_amdgcn_mfma_f32_16x16x32_bf16(kc11, qA1, sb0A, 0, 0, 0);
    f32x4 sb1A = __builtin_amdgcn_mfma_f32_16x16x32_bf16(kc12, qA0, zero, 0, 0, 0);
    sb1A = __builtin_amdgcn_mfma_f32_16x16x32_bf16(kc13, qA1, sb1A, 0, 0, 0);
    f32x4 sb0B = __builtin_amdgcn_mfma_f32_16x16x32_bf16(kc10, qB0, zero, 0, 0, 0);
    sb0B = __builtin_amdgcn_mfma_f32_16x16x32_bf16(kc11, qB1, sb0B, 0, 0, 0);
    f32x4 sb1B = __builtin_amdgcn_mfma_f32_16x16x32_bf16(kc12, qB0, zero, 0, 0, 0);
    sb1B = __builtin_amdgcn_mfma_f32_16x16x32_bf16(kc13, qB1, sb1B, 0, 0, 0);

    // prefetch next step's K for both chains (chain1's last prefetch = masked step)
    Kp0 += 32 * DH;
    kc00 = *(const bf16x8*)(Kp0);
    kc01 = *(const bf16x8*)(Kp0 + 32);
    kc02 = *(const bf16x8*)(Kp0 + 16 * DH);
    kc03 = *(const bf16x8*)(Kp0 + 16 * DH + 32);
    Kp1 += 32 * DH;
    kc10 = *(const bf16x8*)(Kp1);
    kc11 = *(const bf16x8*)(Kp1 + 32);
    kc12 = *(const bf16x8*)(Kp1 + 16 * DH);
    kc13 = *(const bf16x8*)(Kp1 + 16 * DH + 32);

    float a0A[8], a0B[8], a1A[8], a1B[8];
#pragma unroll
    for (int r = 0; r < 4; r++) {
      a0A[r] = sa0A[r]; a0A[4 + r] = sa1A[r];
      a0B[r] = sa0B[r]; a0B[4 + r] = sa1B[r];
      a1A[r] = sb0A[r]; a1A[4 + r] = sb1A[r];
      a1B[r] = sb0B[r]; a1B[4 + r] = sb1B[r];
    }
    sm_pv(a0A, mA, lA, va0, va1, va2, va3, oA);
    sm_pv(a0B, mB, lB, va0, va1, va2, va3, oB);
    sm_pv(a1A, mA, lA, vb0, vb1, vb2, vb3, oA);
    sm_pv(a1B, mB, lB, vb0, vb1, vb2, vb3, oB);
  }

  // ---- optional solo chain0 step (nst even): kc0 holds step jn = half-1 ----
  if (solo) {
    bf16x8 va0 = *(const bf16x8*)(Vp0);
    bf16x8 va1 = *(const bf16x8*)(Vp0 + 16 * S_LEN);
    bf16x8 va2 = *(const bf16x8*)(Vp0 + 32 * S_LEN);
    bf16x8 va3 = *(const bf16x8*)(Vp0 + 48 * S_LEN);

    f32x4 s0A = __builtin_amdgcn_mfma_f32_16x16x32_bf16(kc00, qA0, zero, 0, 0, 0);
    s0A = __builtin_amdgcn_mfma_f32_16x16x32_bf16(kc01, qA1, s0A, 0, 0, 0);
    f32x4 s1A = __builtin_amdgcn_mfma_f32_16x16x32_bf16(kc02, qA0, zero, 0, 0, 0);
    s1A = __builtin_amdgcn_mfma_f32_16x16x32_bf16(kc03, qA1, s1A, 0, 0, 0);
    f32x4 s0B = __builtin_amdgcn_mfma_f32_16x16x32_bf16(kc00, qB0, zero, 0, 0, 0);
    s0B = __builtin_amdgcn_mfma_f32_16x16x32_bf16(kc01, qB1, s0B, 0, 0, 0);
    f32x4 s1B = __builtin_amdgcn_mfma_f32_16x16x32_bf16(kc02, qB0, zero, 0, 0, 0);
    s1B = __builtin_amdgcn_mfma_f32_16x16x32_bf16(kc03, qB1, s1B, 0, 0, 0);

    float aA[8], aB[8];
#pragma unroll
    for (int r = 0; r < 4; r++) {
      aA[r] = s0A[r]; aA[4 + r] = s1A[r];
      aB[r] = s0B[r]; aB[4 + r] = s1B[r];
    }
    sm_pv(aA, mA, lA, va0, va1, va2, va3, oA);
    sm_pv(aB, mB, lB, va0, va1, va2, va3, oB);
  }

  // ---- chain1 masked diagonal step: kc1 holds step nst-1 (both parities) ----
  {
    bf16x8 vb0 = *(const bf16x8*)(Vp1);
    bf16x8 vb1 = *(const bf16x8*)(Vp1 + 16 * S_LEN);
    bf16x8 vb2 = *(const bf16x8*)(Vp1 + 32 * S_LEN);
    bf16x8 vb3 = *(const bf16x8*)(Vp1 + 48 * S_LEN);

    f32x4 s0A = __builtin_amdgcn_mfma_f32_16x16x32_bf16(kc10, qA0, zero, 0, 0, 0);
    s0A = __builtin_amdgcn_mfma_f32_16x16x32_bf16(kc11, qA1, s0A, 0, 0, 0);
    f32x4 s1A = __builtin_amdgcn_mfma_f32_16x16x32_bf16(kc12, qA0, zero, 0, 0, 0);
    s1A = __builtin_amdgcn_mfma_f32_16x16x32_bf16(kc13, qA1, s1A, 0, 0, 0);
    f32x4 s0B = __builtin_amdgcn_mfma_f32_16x16x32_bf16(kc10, qB0, zero, 0, 0, 0);
    s0B = __builtin_amdgcn_mfma_f32_16x16x32_bf16(kc11, qB1, s0B, 0, 0, 0);
    f32x4 s1B = __builtin_amdgcn_mfma_f32_16x16x32_bf16(kc12, qB0, zero, 0, 0, 0);
    s1B = __builtin_amdgcn_mfma_f32_16x16x32_bf16(kc13, qB1, s1B, 0, 0, 0);

    // A group: q = qbase+lr; valid iff kv row qbase+lg*4+r (+16) <= q
    const int qrelA = lr - lg * 4;
    const int qrelB = qrelA + 16;
    float aA[8], aB[8];
#pragma unroll
    for (int r = 0; r < 4; r++) {
      aA[r]     = (r <= qrelA)      ? s0A[r] : -__builtin_inff();
      aA[4 + r] = (r + 16 <= qrelA) ? s1A[r] : -__builtin_inff();  // never valid
      aB[r]     = s0B[r];                                          // always valid
      aB[4 + r] = (r + 16 <= qrelB) ? s1B[r] : -__builtin_inff();
    }
    sm_pv(aA, mA, lA, vb0, vb1, vb2, vb3, oA);
    sm_pv(aB, mB, lB, vb0, vb1, vb2, vb3, oB);
  }

  // ---- epilogue: lane holds q=lr, d = dt*16 + lg*4 + r ----
  lA += __shfl_xor(lA, 16); lA += __shfl_xor(lA, 32);
  lB += __shfl_xor(lB, 16); lB += __shfl_xor(lB, 32);
  const float rlA = __builtin_amdgcn_rcpf(lA);
  const float rlB = __builtin_amdgcn_rcpf(lB);

  const int b = bh >> 4, h = bh & 15;
  const size_t obaseA = ((size_t)b * S_LEN + qbase + lr) * DM + h * DH;
  const size_t obaseB = obaseA + (size_t)16 * DM;
#pragma unroll
  for (int dt = 0; dt < 4; dt++) {
    u32x2 pkA, pkB;
    pkA.x = pkbf(oA[dt][0] * rlA, oA[dt][1] * rlA);
    pkA.y = pkbf(oA[dt][2] * rlA, oA[dt][3] * rlA);
    pkB.x = pkbf(oB[dt][0] * rlB, oB[dt][1] * rlB);
    pkB.y = pkbf(oB[dt][2] * rlB, oB[dt][3] * rlB);
    *(u32x2*)(Oo + obaseA + dt * 16 + lg * 4) = pkA;
    *(u32x2*)(Oo + obaseB + dt * 16 + lg * 4) = pkB;
  }
}

// ---------------- host launcher ----------------
extern "C" void kernel_launch(void* const* d_in, const int* in_sizes, int n_in,
                              void* d_out, int out_size, void* d_ws, size_t ws_size,
                              hipStream_t stream) {
  const float* x  = (const float*)d_in[0];
  const float* Wq = (const float*)d_in[1];
  const float* bq = (const float*)d_in[2];
  const float* Wk = (const float*)d_in[3];
  const float* bk = (const float*)d_in[4];
  const float* Wv = (const float*)d_in[5];
  const float* bv = (const float*)d_in[6];
  const float* Wo = (const float*)d_in[7];
  const float* bo = (const float*)d_in[8];

  char* ws = (char*)d_ws;
  u16* xb    = (u16*)(ws);                 // 8 MB  [4096,1024] bf16
  u16* wb    = (u16*)(ws + (8u << 20));    // 8 MB  Wq,Wk,Wv,Wo bf16
  u16* Qb    = (u16*)(ws + (16u << 20));   // 8 MB  [B,H,S,Dh]
  u16* Kb    = (u16*)(ws + (24u << 20));   // 8 MB  [B,H,S,Dh]
  u16* Vtb   = (u16*)(ws + (32u << 20));   // 8 MB  [B,H,Dh,S] (s-permuted)
  u16* AOb   = (u16*)(ws + (40u << 20));   // 8 MB  [B*S, DM]
  float2* rt = (float2*)(ws + (48u << 20));            // 512 KB rope table
  float* kmx = (float*)(ws + (48u << 20) + (512u << 10));  // 128 B kmax[32]

  convert_k<<<8192, 256, 0, stream>>>(x, Wq, Wk, Wv, Wo, xb, wb);
  rope_k<<<256, 256, 0, stream>>>(rt, kmx);
  gemm_k<<<768, 256, 0, stream>>>(xb, wb, wb + (1u << 20), wb + (2u << 20),
                                  bq, bk, bv, rt, Qb, Kb, Vtb, 0);
  knorm_k<<<256, 256, 0, stream>>>(Kb, kmx);
  attn_k<<<2048, 64, 0, stream>>>(Qb, Kb, Vtb, AOb, kmx);
  gemm_k<<<256, 256, 0, stream>>>(AOb, wb + (3u << 20), wb + (3u << 20), wb + (3u << 20),
                                  bo, bo, bo, rt, d_out, d_out, d_out, 3);
}

// Round 14
// 158.007 us; speedup vs baseline: 1.0846x; 1.0832x over previous
//
#include <hip/hip_runtime.h>
#include <stdint.h>

#define S_LEN 2048
#define BATCH 2
#define DM 1024
#define NH 16
#define DH 64
#define MROWS 4096  // BATCH * S_LEN

typedef unsigned short u16;
typedef unsigned int u32;
typedef __attribute__((ext_vector_type(8))) short bf16x8;
typedef __attribute__((ext_vector_type(4))) float f32x4;
typedef __attribute__((ext_vector_type(2))) unsigned u32x2;

union pack8 { u32 w[4]; bf16x8 v8; };

__device__ inline u16 f2bf(float f) {
  union { float f; unsigned u; } v; v.f = f;
  unsigned u = v.u;
  unsigned r = u + 0x7fffu + ((u >> 16) & 1u);
  return (u16)(r >> 16);
}

__device__ inline u32 pkbf(float lo, float hi) {
  u32 r;
  asm("v_cvt_pk_bf16_f32 %0, %1, %2" : "=v"(r) : "v"(lo), "v"(hi));
  return r;
}

__device__ inline float bf2f(short s) {
  union { u32 u; float f; } c; c.u = ((u32)(u16)s) << 16;
  return c.f;
}

// async global -> LDS, 16B per lane; LDS dest is wave-uniform base + lane*16
__device__ __forceinline__ void gload_lds16(const u16* g, u16* l) {
  __builtin_amdgcn_global_load_lds(
      (const __attribute__((address_space(1))) u32*)g,
      (__attribute__((address_space(3))) u32*)l, 16, 0, 0);
}

// ---------------- fp32 -> bf16 conversion for x, Wq, Wk, Wv, Wo ----------------
__global__ void convert_k(const float* __restrict__ x, const float* __restrict__ wq,
                          const float* __restrict__ wk, const float* __restrict__ wv,
                          const float* __restrict__ wo, u16* __restrict__ xb,
                          u16* __restrict__ wb) {
  int i = blockIdx.x * blockDim.x + threadIdx.x;
  const int total = (MROWS * DM + 4 * DM * DM) / 4;  // 2,097,152 float4 groups
  if (i >= total) return;
  int e = i * 4;
  const float* src;
  u16* dst;
  if (e < MROWS * DM) {
    src = x + e; dst = xb + e;
  } else {
    int j = e - MROWS * DM;
    int w = j >> 20;
    int o = j & ((1 << 20) - 1);
    src = (w == 0) ? wq + o : (w == 1) ? wk + o : (w == 2) ? wv + o : wo + o;
    dst = wb + j;
  }
  float4 v = *(const float4*)src;
  uint2 r;
  r.x = (unsigned)f2bf(v.x) | ((unsigned)f2bf(v.y) << 16);
  r.y = (unsigned)f2bf(v.z) | ((unsigned)f2bf(v.w) << 16);
  *(uint2*)dst = r;
}

// ---------------- RoPE cos/sin table [S][32]; also zero kmax[32] ----------------
__global__ void rope_k(float2* __restrict__ tab, float* __restrict__ kmax) {
  int i = blockIdx.x * blockDim.x + threadIdx.x;
  if (i < 32) kmax[i] = 0.f;
  if (i >= S_LEN * 32) return;
  int s = i >> 5, p = i & 31;
  float inv = expf(-(float)p * 0.28782313662425575f);  // ln(10000)/32
  float a = (float)s * inv;
  tab[i] = make_float2(cosf(a), sinf(a));
}

// ---------------- per-bh max row norm of K (for static softmax bound) ----------------
__global__ void knorm_k(const u16* __restrict__ K, float* __restrict__ kmax) {
  const int row = blockIdx.x * 256 + threadIdx.x;  // 65536 rows = B*H*S
  const int bh = row >> 11;
  const u16* p = K + (size_t)row * DH;
  float ss = 0.f;
#pragma unroll
  for (int i = 0; i < 8; i++) {
    bf16x8 v = *(const bf16x8*)(p + i * 8);
#pragma unroll
    for (int j = 0; j < 8; j++) { float f = bf2f(v[j]); ss += f * f; }
  }
  float kn = sqrtf(ss);
#pragma unroll
  for (int d = 1; d < 64; d <<= 1) kn = fmaxf(kn, __shfl_xor(kn, d));
  if ((threadIdx.x & 63) == 0)
    atomicMax((unsigned*)(kmax + bh), __float_as_uint(kn));
}

// ---------------- GEMM: C = A @ W^T + bias, fused epilogues ----------------
// mode 0: Q  -> rope, *0.125*log2e, bf16 [B,H,S,Dh]   (log2e folded so attn uses exp2)
// mode 1: K  -> rope, bf16 [B,H,S,Dh]
// mode 2: V  -> bf16 [B,H,Dh,S] with per-32 s-block permutation matching the
//               attn PV fragment (pos = ((j&15)>>2)*8 + (j>>4)*4 + (j&3))
// mode 3: O  -> fp32 [M, DM]
__launch_bounds__(256)
__global__ void gemm_k(const u16* __restrict__ A,
                       const u16* __restrict__ w0, const u16* __restrict__ w1,
                       const u16* __restrict__ w2,
                       const float* __restrict__ b0, const float* __restrict__ b1,
                       const float* __restrict__ b2,
                       const float2* __restrict__ rope,
                       void* __restrict__ o0, void* __restrict__ o1, void* __restrict__ o2,
                       int mode0) {
  const int mode = mode0 + (int)(blockIdx.x >> 8);
  const int tile = blockIdx.x & 255;
  const int mt = tile >> 3, nt = tile & 7;
  const int mbase = mt * 128, nbase = nt * 128;
  const u16* W = (mode == 1) ? w1 : (mode == 2) ? w2 : w0;
  const float* bias = (mode == 1) ? b1 : (mode == 2) ? b2 : b0;
  void* outp = (mode == 1) ? o1 : (mode == 2) ? o2 : o0;

  __shared__ u16 As[128 * 40];  // padded row stride 40 (2-way bank aliasing = free)
  __shared__ u16 Bs[128 * 40];

  const int t = threadIdx.x;
  const int lane = t & 63, wvi = t >> 6;
  const int lr = lane & 15, lg = lane >> 4;
  const int wm = (wvi >> 1) * 64, wn = (wvi & 1) * 64;

  f32x4 acc[4][4] = {};
  const int srow = t >> 2;        // 0..63
  const int scol = (t & 3) * 8;   // 0,8,16,24

  for (int kk = 0; kk < DM; kk += 32) {
    bf16x8 a0 = *(const bf16x8*)(A + (size_t)(mbase + srow) * DM + kk + scol);
    bf16x8 a1 = *(const bf16x8*)(A + (size_t)(mbase + 64 + srow) * DM + kk + scol);
    bf16x8 g0 = *(const bf16x8*)(W + (size_t)(nbase + srow) * DM + kk + scol);
    bf16x8 g1 = *(const bf16x8*)(W + (size_t)(nbase + 64 + srow) * DM + kk + scol);
    __syncthreads();
    *(bf16x8*)&As[srow * 40 + scol] = a0;
    *(bf16x8*)&As[(64 + srow) * 40 + scol] = a1;
    *(bf16x8*)&Bs[srow * 40 + scol] = g0;
    *(bf16x8*)&Bs[(64 + srow) * 40 + scol] = g1;
    __syncthreads();
    bf16x8 af[4], bfr[4];
#pragma unroll
    for (int mi = 0; mi < 4; mi++)
      af[mi] = *(const bf16x8*)&As[(wm + mi * 16 + lr) * 40 + lg * 8];
#pragma unroll
    for (int ni = 0; ni < 4; ni++)
      bfr[ni] = *(const bf16x8*)&Bs[(wn + ni * 16 + lr) * 40 + lg * 8];
#pragma unroll
    for (int mi = 0; mi < 4; mi++)
#pragma unroll
      for (int ni = 0; ni < 4; ni++)
        acc[mi][ni] = __builtin_amdgcn_mfma_f32_16x16x32_bf16(af[mi], bfr[ni], acc[mi][ni], 0, 0, 0);
  }

#pragma unroll
  for (int ni = 0; ni < 4; ni++) {
    const int col = nbase + wn + ni * 16 + lr;
    const float bv = bias[col];
#pragma unroll
    for (int mi = 0; mi < 4; mi++) {
      const int row0 = mbase + wm + mi * 16 + lg * 4;
      f32x4 v = acc[mi][ni];
#pragma unroll
      for (int r = 0; r < 4; r++) {
        float val = v[r] + bv;
        const int row = row0 + r;
        if (mode <= 1) {
          float nb = __shfl_xor(val, 1);
          const int d = col & 63, p = d >> 1, s = row & (S_LEN - 1);
          float2 cs = rope[s * 32 + p];
          float ov = (d & 1) ? (nb * cs.y + val * cs.x) : (val * cs.x - nb * cs.y);
          if (mode == 0) ov *= 0.18033688011112042f;  // 1/sqrt(Dh) * log2(e)
          const int b = row >> 11, h = col >> 6;
          ((u16*)outp)[((size_t)(b * NH + h) * S_LEN + s) * DH + d] = f2bf(ov);
        } else if (mode == 2) {
          const int b = row >> 11, h = col >> 6, d = col & 63, s = row & (S_LEN - 1);
          const int j = s & 31;
          const int pos = (s & ~31) + (((j & 15) >> 2) << 3) + ((j >> 4) << 2) + (j & 3);
          ((u16*)outp)[((size_t)(b * NH + h) * DH + d) * S_LEN + pos] = f2bf(val);
        } else {
          ((float*)outp)[(size_t)row * DM + col] = val;
        }
      }
    }
  }
}

// ---- static-bound softmax + PV for one q-group: accumulate into o[4] ----
__device__ __forceinline__ void sm_pv(const float a[8], float m, float& l,
                                      bf16x8 v0, bf16x8 v1, bf16x8 v2, bf16x8 v3,
                                      f32x4* o) {
  float p[8];
#pragma unroll
  for (int r = 0; r < 8; r++) p[r] = __builtin_amdgcn_exp2f(a[r] - m);
  l += ((p[0] + p[1]) + (p[2] + p[3])) + ((p[4] + p[5]) + (p[6] + p[7]));
  pack8 pu;
  pu.w[0] = pkbf(p[0], p[1]);
  pu.w[1] = pkbf(p[2], p[3]);
  pu.w[2] = pkbf(p[4], p[5]);
  pu.w[3] = pkbf(p[6], p[7]);
  o[0] = __builtin_amdgcn_mfma_f32_16x16x32_bf16(v0, pu.v8, o[0], 0, 0, 0);
  o[1] = __builtin_amdgcn_mfma_f32_16x16x32_bf16(v1, pu.v8, o[1], 0, 0, 0);
  o[2] = __builtin_amdgcn_mfma_f32_16x16x32_bf16(v2, pu.v8, o[2], 0, 0, 0);
  o[3] = __builtin_amdgcn_mfma_f32_16x16x32_bf16(v3, pu.v8, o[3], 0, 0, 0);
}

// ---------------- causal flash attention: LDS-staged K/V, 4 waves/block ----------------
// Block = 4 waves, one bh, q-tiles {4g..4g+3} (wave w owns tile 4g+w, QBLK=32).
// Per 32-kv step: stage next K(32x64)+V(64x32) tiles into the alternate LDS buffer
// via global_load_lds (no VGPR pressure; the barrier's vmcnt drain = structural
// prefetch the compiler can't sink). LDS is XOR-swizzled via PRE-SWIZZLED GLOBAL
// source (K: colB^=(row&7)<<4, V: colB^=(row&3)<<4) so ds_read_b128 fragments are
// conflict-free. Causality: one generic branch-free mask per step (steps past a
// wave's diagonal give exp2(-inf)=0 under the static bound -> safe, <=3 wasted).
__launch_bounds__(256)
__global__ void attn_k(const u16* __restrict__ Q, const u16* __restrict__ K,
                       const u16* __restrict__ Vt, u16* __restrict__ Oo,
                       const float* __restrict__ kmax) {
  const int bh = blockIdx.x & 31;
  const int g = 15 - (int)(blockIdx.x >> 5);   // longest-first
  const int tid = threadIdx.x;
  const int w = tid >> 6;
  const int lane = tid & 63;
  const int lr = lane & 15, lg = lane >> 4;
  const int tile = g * 4 + w;
  const int qbase = tile * 32;
  const int nst = g * 4 + 4;                   // steps for the whole block

  __shared__ u16 Ks[2][2048];                  // [buf][32 x 64] bf16, swizzled
  __shared__ u16 Vs[2][2048];                  // [buf][64 x 32] bf16, swizzled

  const u16* Kg = K + (size_t)bh * S_LEN * DH;
  const u16* Vg = Vt + (size_t)bh * DH * S_LEN;

  // staging indices (tid-static)
  const int kr = tid >> 3, kcB = (tid & 7) << 4;
  const int vr = tid >> 2, vcB = (tid & 3) << 4;
  const int ksrcoff = ((kcB ^ ((kr & 7) << 4)) >> 1);
  const int vsrcoff = ((vcB ^ ((vr & 3) << 4)) >> 1);

  // ---- Q fragments + static softmax bound ----
  const size_t qoff = ((size_t)bh * S_LEN + qbase + lr) * DH + lg * 8;
  const bf16x8 qA0 = *(const bf16x8*)(Q + qoff);
  const bf16x8 qA1 = *(const bf16x8*)(Q + qoff + 32);
  const bf16x8 qB0 = *(const bf16x8*)(Q + qoff + 16 * DH);
  const bf16x8 qB1 = *(const bf16x8*)(Q + qoff + 16 * DH + 32);

  float ssA = 0.f, ssB = 0.f;
#pragma unroll
  for (int j = 0; j < 8; j++) {
    float a0 = bf2f(qA0[j]), a1 = bf2f(qA1[j]);
    float b0 = bf2f(qB0[j]), b1 = bf2f(qB1[j]);
    ssA += a0 * a0 + a1 * a1;
    ssB += b0 * b0 + b1 * b1;
  }
  ssA += __shfl_xor(ssA, 16); ssA += __shfl_xor(ssA, 32);
  ssB += __shfl_xor(ssB, 16); ssB += __shfl_xor(ssB, 32);
  const float kmx = kmax[bh];
  const float mA = sqrtf(ssA) * kmx;
  const float mB = sqrtf(ssB) * kmx;

  f32x4 oA[4] = {}, oB[4] = {};
  float lA = 0.f, lB = 0.f;
  const f32x4 zero = {};

  // fragment read offsets (swizzled)
  const int kmsk = (lr & 7) << 4;
  const int k00 = lr * 64 + (((lg << 4)) ^ kmsk) / 2;
  const int k01 = lr * 64 + ((64 + (lg << 4)) ^ kmsk) / 2;
  const int k10 = (16 + lr) * 64 + (((lg << 4)) ^ kmsk) / 2;
  const int k11 = (16 + lr) * 64 + ((64 + (lg << 4)) ^ kmsk) / 2;
  const int vmsk = (lr & 3) << 4;
  const int vo = ((lg << 4) ^ vmsk) / 2;

  // ---- prologue: stage step 0 into buf 0 ----
  gload_lds16(Kg + (size_t)kr * DH + ksrcoff, &Ks[0][w << 9]);
  gload_lds16(Vg + (size_t)vr * S_LEN + vsrcoff, &Vs[0][w << 9]);

  for (int s = 0; s < nst; ++s) {
    const int b = s & 1;
    if (s + 1 < nst) {  // stage next step into the other buffer
      gload_lds16(Kg + (size_t)((s + 1) * 32 + kr) * DH + ksrcoff, &Ks[b ^ 1][w << 9]);
      gload_lds16(Vg + (size_t)vr * S_LEN + (s + 1) * 32 + vsrcoff, &Vs[b ^ 1][w << 9]);
    }
    __syncthreads();  // vmcnt(0) drain: buf b complete everywhere

    const u16* Kb = Ks[b];
    const u16* Vb = Vs[b];
    bf16x8 kc0 = *(const bf16x8*)&Kb[k00];
    bf16x8 kc1 = *(const bf16x8*)&Kb[k01];
    bf16x8 kc2 = *(const bf16x8*)&Kb[k10];
    bf16x8 kc3 = *(const bf16x8*)&Kb[k11];
    bf16x8 v0 = *(const bf16x8*)&Vb[(lr) * 32 + vo];
    bf16x8 v1 = *(const bf16x8*)&Vb[(16 + lr) * 32 + vo];
    bf16x8 v2 = *(const bf16x8*)&Vb[(32 + lr) * 32 + vo];
    bf16x8 v3 = *(const bf16x8*)&Vb[(48 + lr) * 32 + vo];

    f32x4 s0A = __builtin_amdgcn_mfma_f32_16x16x32_bf16(kc0, qA0, zero, 0, 0, 0);
    s0A = __builtin_amdgcn_mfma_f32_16x16x32_bf16(kc1, qA1, s0A, 0, 0, 0);
    f32x4 s1A = __builtin_amdgcn_mfma_f32_16x16x32_bf16(kc2, qA0, zero, 0, 0, 0);
    s1A = __builtin_amdgcn_mfma_f32_16x16x32_bf16(kc3, qA1, s1A, 0, 0, 0);
    f32x4 s0B = __builtin_amdgcn_mfma_f32_16x16x32_bf16(kc0, qB0, zero, 0, 0, 0);
    s0B = __builtin_amdgcn_mfma_f32_16x16x32_bf16(kc1, qB1, s0B, 0, 0, 0);
    f32x4 s1B = __builtin_amdgcn_mfma_f32_16x16x32_bf16(kc2, qB0, zero, 0, 0, 0);
    s1B = __builtin_amdgcn_mfma_f32_16x16x32_bf16(kc3, qB1, s1B, 0, 0, 0);

    // generic causal mask (passes automatically for steps below the diagonal)
    const int qrelA = qbase + lr - (s << 5) - (lg << 2);
    const int qrelB = qrelA + 16;
    float aA[8], aB[8];
#pragma unroll
    for (int r = 0; r < 4; r++) {
      aA[r]     = (r <= qrelA)      ? s0A[r] : -__builtin_inff();
      aA[4 + r] = (r + 16 <= qrelA) ? s1A[r] : -__builtin_inff();
      aB[r]     = (r <= qrelB)      ? s0B[r] : -__builtin_inff();
      aB[4 + r] = (r + 16 <= qrelB) ? s1B[r] : -__builtin_inff();
    }
    sm_pv(aA, mA, lA, v0, v1, v2, v3, oA);
    sm_pv(aB, mB, lB, v0, v1, v2, v3, oB);

    __syncthreads();  // all reads of buf b done before it is re-staged
  }

  // ---- epilogue: lane holds q=lr, d = dt*16 + lg*4 + r ----
  lA += __shfl_xor(lA, 16); lA += __shfl_xor(lA, 32);
  lB += __shfl_xor(lB, 16); lB += __shfl_xor(lB, 32);
  const float rlA = __builtin_amdgcn_rcpf(lA);
  const float rlB = __builtin_amdgcn_rcpf(lB);

  const int bb = bh >> 4, h = bh & 15;
  const size_t obaseA = ((size_t)bb * S_LEN + qbase + lr) * DM + h * DH;
  const size_t obaseB = obaseA + (size_t)16 * DM;
#pragma unroll
  for (int dt = 0; dt < 4; dt++) {
    u32x2 pkA, pkB;
    pkA.x = pkbf(oA[dt][0] * rlA, oA[dt][1] * rlA);
    pkA.y = pkbf(oA[dt][2] * rlA, oA[dt][3] * rlA);
    pkB.x = pkbf(oB[dt][0] * rlB, oB[dt][1] * rlB);
    pkB.y = pkbf(oB[dt][2] * rlB, oB[dt][3] * rlB);
    *(u32x2*)(Oo + obaseA + dt * 16 + lg * 4) = pkA;
    *(u32x2*)(Oo + obaseB + dt * 16 + lg * 4) = pkB;
  }
}

// ---------------- host launcher ----------------
extern "C" void kernel_launch(void* const* d_in, const int* in_sizes, int n_in,
                              void* d_out, int out_size, void* d_ws, size_t ws_size,
                              hipStream_t stream) {
  const float* x  = (const float*)d_in[0];
  const float* Wq = (const float*)d_in[1];
  const float* bq = (const float*)d_in[2];
  const float* Wk = (const float*)d_in[3];
  const float* bk = (const float*)d_in[4];
  const float* Wv = (const float*)d_in[5];
  const float* bv = (const float*)d_in[6];
  const float* Wo = (const float*)d_in[7];
  const float* bo = (const float*)d_in[8];

  char* ws = (char*)d_ws;
  u16* xb    = (u16*)(ws);                 // 8 MB  [4096,1024] bf16
  u16* wb    = (u16*)(ws + (8u << 20));    // 8 MB  Wq,Wk,Wv,Wo bf16
  u16* Qb    = (u16*)(ws + (16u << 20));   // 8 MB  [B,H,S,Dh]
  u16* Kb    = (u16*)(ws + (24u << 20));   // 8 MB  [B,H,S,Dh]
  u16* Vtb   = (u16*)(ws + (32u << 20));   // 8 MB  [B,H,Dh,S] (s-permuted)
  u16* AOb   = (u16*)(ws + (40u << 20));   // 8 MB  [B*S, DM]
  float2* rt = (float2*)(ws + (48u << 20));            // 512 KB rope table
  float* kmx = (float*)(ws + (48u << 20) + (512u << 10));  // 128 B kmax[32]

  convert_k<<<8192, 256, 0, stream>>>(x, Wq, Wk, Wv, Wo, xb, wb);
  rope_k<<<256, 256, 0, stream>>>(rt, kmx);
  gemm_k<<<768, 256, 0, stream>>>(xb, wb, wb + (1u << 20), wb + (2u << 20),
                                  bq, bk, bv, rt, Qb, Kb, Vtb, 0);
  knorm_k<<<256, 256, 0, stream>>>(Kb, kmx);
  attn_k<<<512, 256, 0, stream>>>(Qb, Kb, Vtb, AOb, kmx);
  gemm_k<<<256, 256, 0, stream>>>(AOb, wb + (3u << 20), wb + (3u << 20), wb + (3u << 20),
                                  bo, bo, bo, rt, d_out, d_out, d_out, 3);
}

// Round 15
// 153.858 us; speedup vs baseline: 1.1139x; 1.0270x over previous
//
#include <hip/hip_runtime.h>
#include <stdint.h>

#define S_LEN 2048
#define BATCH 2
#define DM 1024
#define NH 16
#define DH 64
#define MROWS 4096  // BATCH * S_LEN

typedef unsigned short u16;
typedef unsigned int u32;
typedef __attribute__((ext_vector_type(8))) short bf16x8;
typedef __attribute__((ext_vector_type(4))) float f32x4;
typedef __attribute__((ext_vector_type(2))) unsigned u32x2;

union pack8 { u32 w[4]; bf16x8 v8; };

__device__ inline u16 f2bf(float f) {
  union { float f; unsigned u; } v; v.f = f;
  unsigned u = v.u;
  unsigned r = u + 0x7fffu + ((u >> 16) & 1u);
  return (u16)(r >> 16);
}

__device__ inline u32 pkbf(float lo, float hi) {
  u32 r;
  asm("v_cvt_pk_bf16_f32 %0, %1, %2" : "=v"(r) : "v"(lo), "v"(hi));
  return r;
}

__device__ inline float bf2f(short s) {
  union { u32 u; float f; } c; c.u = ((u32)(u16)s) << 16;
  return c.f;
}

// async global -> LDS, 16B per lane; LDS dest is wave-uniform base + lane*16
__device__ __forceinline__ void gload_lds16(const u16* g, u16* l) {
  __builtin_amdgcn_global_load_lds(
      (const __attribute__((address_space(1))) u32*)g,
      (__attribute__((address_space(3))) u32*)l, 16, 0, 0);
}

// ---------------- fp32 -> bf16 conversion for x, Wq, Wk, Wv, Wo ----------------
__global__ void convert_k(const float* __restrict__ x, const float* __restrict__ wq,
                          const float* __restrict__ wk, const float* __restrict__ wv,
                          const float* __restrict__ wo, u16* __restrict__ xb,
                          u16* __restrict__ wb) {
  int i = blockIdx.x * blockDim.x + threadIdx.x;
  const int total = (MROWS * DM + 4 * DM * DM) / 4;  // 2,097,152 float4 groups
  if (i >= total) return;
  int e = i * 4;
  const float* src;
  u16* dst;
  if (e < MROWS * DM) {
    src = x + e; dst = xb + e;
  } else {
    int j = e - MROWS * DM;
    int w = j >> 20;
    int o = j & ((1 << 20) - 1);
    src = (w == 0) ? wq + o : (w == 1) ? wk + o : (w == 2) ? wv + o : wo + o;
    dst = wb + j;
  }
  float4 v = *(const float4*)src;
  uint2 r;
  r.x = (unsigned)f2bf(v.x) | ((unsigned)f2bf(v.y) << 16);
  r.y = (unsigned)f2bf(v.z) | ((unsigned)f2bf(v.w) << 16);
  *(uint2*)dst = r;
}

// ---------------- RoPE cos/sin table [S][32]; also zero kmax[32] ----------------
__global__ void rope_k(float2* __restrict__ tab, float* __restrict__ kmax) {
  int i = blockIdx.x * blockDim.x + threadIdx.x;
  if (i < 32) kmax[i] = 0.f;
  if (i >= S_LEN * 32) return;
  int s = i >> 5, p = i & 31;
  float inv = expf(-(float)p * 0.28782313662425575f);  // ln(10000)/32
  float a = (float)s * inv;
  tab[i] = make_float2(cosf(a), sinf(a));
}

// ---------------- per-bh max row norm of K (for static softmax bound) ----------------
__global__ void knorm_k(const u16* __restrict__ K, float* __restrict__ kmax) {
  const int row = blockIdx.x * 256 + threadIdx.x;  // 65536 rows = B*H*S
  const int bh = row >> 11;
  const u16* p = K + (size_t)row * DH;
  float ss = 0.f;
#pragma unroll
  for (int i = 0; i < 8; i++) {
    bf16x8 v = *(const bf16x8*)(p + i * 8);
#pragma unroll
    for (int j = 0; j < 8; j++) { float f = bf2f(v[j]); ss += f * f; }
  }
  float kn = sqrtf(ss);
#pragma unroll
  for (int d = 1; d < 64; d <<= 1) kn = fmaxf(kn, __shfl_xor(kn, d));
  if ((threadIdx.x & 63) == 0)
    atomicMax((unsigned*)(kmax + bh), __float_as_uint(kn));
}

// ---------------- GEMM: C = A @ W^T + bias, fused epilogues ----------------
// m97 structure: linear [128][32] LDS tiles staged via global_load_lds width-16
// (no VGPR round-trip), 2-barrier K-loop. Epilogues unchanged.
// mode 0: Q  -> rope, *0.125*log2e, bf16 [B,H,S,Dh]
// mode 1: K  -> rope, bf16 [B,H,S,Dh]
// mode 2: V  -> bf16 [B,H,Dh,S] s-permuted for the attn PV fragment
// mode 3: O  -> fp32 [M, DM]
__launch_bounds__(256)
__global__ void gemm_k(const u16* __restrict__ A,
                       const u16* __restrict__ w0, const u16* __restrict__ w1,
                       const u16* __restrict__ w2,
                       const float* __restrict__ b0, const float* __restrict__ b1,
                       const float* __restrict__ b2,
                       const float2* __restrict__ rope,
                       void* __restrict__ o0, void* __restrict__ o1, void* __restrict__ o2,
                       int mode0) {
  const int mode = mode0 + (int)(blockIdx.x >> 8);
  const int tile = blockIdx.x & 255;
  const int mt = tile >> 3, nt = tile & 7;
  const int mbase = mt * 128, nbase = nt * 128;
  const u16* W = (mode == 1) ? w1 : (mode == 2) ? w2 : w0;
  const float* bias = (mode == 1) ? b1 : (mode == 2) ? b2 : b0;
  void* outp = (mode == 1) ? o1 : (mode == 2) ? o2 : o0;

  __shared__ u16 As[128 * 32];  // 8 KB, linear (global_load_lds writes linearly)
  __shared__ u16 Bs[128 * 32];

  const int t = threadIdx.x;
  const int lane = t & 63, wvi = t >> 6;
  const int lr = lane & 15, lg = lane >> 4;
  const int wm = (wvi >> 1) * 64, wn = (wvi & 1) * 64;

  f32x4 acc[4][4] = {};
  const int srow = t >> 2;        // 0..63 (row within half-tile)
  const int scol = (t & 3) * 8;   // 0,8,16,24 u16

  for (int kk = 0; kk < DM; kk += 32) {
    // stage A/B tiles direct to LDS: 4 x global_load_lds width-16 per thread
    gload_lds16(A + (size_t)(mbase + srow) * DM + kk + scol, &As[wvi * 512]);
    gload_lds16(A + (size_t)(mbase + 64 + srow) * DM + kk + scol, &As[2048 + wvi * 512]);
    gload_lds16(W + (size_t)(nbase + srow) * DM + kk + scol, &Bs[wvi * 512]);
    gload_lds16(W + (size_t)(nbase + 64 + srow) * DM + kk + scol, &Bs[2048 + wvi * 512]);
    __syncthreads();  // vmcnt(0) drain: tiles staged

    bf16x8 af[4], bfr[4];
#pragma unroll
    for (int mi = 0; mi < 4; mi++)
      af[mi] = *(const bf16x8*)&As[(wm + mi * 16 + lr) * 32 + lg * 8];
#pragma unroll
    for (int ni = 0; ni < 4; ni++)
      bfr[ni] = *(const bf16x8*)&Bs[(wn + ni * 16 + lr) * 32 + lg * 8];
#pragma unroll
    for (int mi = 0; mi < 4; mi++)
#pragma unroll
      for (int ni = 0; ni < 4; ni++)
        acc[mi][ni] = __builtin_amdgcn_mfma_f32_16x16x32_bf16(af[mi], bfr[ni], acc[mi][ni], 0, 0, 0);
    __syncthreads();  // all reads done before next stage overwrites
  }

#pragma unroll
  for (int ni = 0; ni < 4; ni++) {
    const int col = nbase + wn + ni * 16 + lr;
    const float bv = bias[col];
#pragma unroll
    for (int mi = 0; mi < 4; mi++) {
      const int row0 = mbase + wm + mi * 16 + lg * 4;
      f32x4 v = acc[mi][ni];
#pragma unroll
      for (int r = 0; r < 4; r++) {
        float val = v[r] + bv;
        const int row = row0 + r;
        if (mode <= 1) {
          float nb = __shfl_xor(val, 1);
          const int d = col & 63, p = d >> 1, s = row & (S_LEN - 1);
          float2 cs = rope[s * 32 + p];
          float ov = (d & 1) ? (nb * cs.y + val * cs.x) : (val * cs.x - nb * cs.y);
          if (mode == 0) ov *= 0.18033688011112042f;  // 1/sqrt(Dh) * log2(e)
          const int b = row >> 11, h = col >> 6;
          ((u16*)outp)[((size_t)(b * NH + h) * S_LEN + s) * DH + d] = f2bf(ov);
        } else if (mode == 2) {
          const int b = row >> 11, h = col >> 6, d = col & 63, s = row & (S_LEN - 1);
          const int j = s & 31;
          const int pos = (s & ~31) + (((j & 15) >> 2) << 3) + ((j >> 4) << 2) + (j & 3);
          ((u16*)outp)[((size_t)(b * NH + h) * DH + d) * S_LEN + pos] = f2bf(val);
        } else {
          ((float*)outp)[(size_t)row * DM + col] = val;
        }
      }
    }
  }
}

// ---- static-bound softmax + PV for one q-group: accumulate into o[4] ----
__device__ __forceinline__ void sm_pv(const float a[8], float m, float& l,
                                      bf16x8 v0, bf16x8 v1, bf16x8 v2, bf16x8 v3,
                                      f32x4* o) {
  float p[8];
#pragma unroll
  for (int r = 0; r < 8; r++) p[r] = __builtin_amdgcn_exp2f(a[r] - m);
  l += ((p[0] + p[1]) + (p[2] + p[3])) + ((p[4] + p[5]) + (p[6] + p[7]));
  pack8 pu;
  pu.w[0] = pkbf(p[0], p[1]);
  pu.w[1] = pkbf(p[2], p[3]);
  pu.w[2] = pkbf(p[4], p[5]);
  pu.w[3] = pkbf(p[6], p[7]);
  o[0] = __builtin_amdgcn_mfma_f32_16x16x32_bf16(v0, pu.v8, o[0], 0, 0, 0);
  o[1] = __builtin_amdgcn_mfma_f32_16x16x32_bf16(v1, pu.v8, o[1], 0, 0, 0);
  o[2] = __builtin_amdgcn_mfma_f32_16x16x32_bf16(v2, pu.v8, o[2], 0, 0, 0);
  o[3] = __builtin_amdgcn_mfma_f32_16x16x32_bf16(v3, pu.v8, o[3], 0, 0, 0);
}

// ---------------- causal flash attention: LDS-staged K/V, 4 waves/block ----------------
// R14 structure. V swizzle FIXED: V's row stride is 64 B (16 banks), so the
// swizzle class must be (row>>1)&3 — (row&3) left same-parity lr rows on the
// same banks (4-way conflict, the measured 1.1M SQ_LDS_BANK_CONFLICT).
// (row>>1)&3 is dt-invariant (16*dt ≡ 0 mod 8) and gives 2 lanes/bank (free).
__launch_bounds__(256)
__global__ void attn_k(const u16* __restrict__ Q, const u16* __restrict__ K,
                       const u16* __restrict__ Vt, u16* __restrict__ Oo,
                       const float* __restrict__ kmax) {
  const int bh = blockIdx.x & 31;
  const int g = 15 - (int)(blockIdx.x >> 5);   // longest-first
  const int tid = threadIdx.x;
  const int w = tid >> 6;
  const int lane = tid & 63;
  const int lr = lane & 15, lg = lane >> 4;
  const int tile = g * 4 + w;
  const int qbase = tile * 32;
  const int nst = g * 4 + 4;                   // steps for the whole block

  __shared__ u16 Ks[2][2048];                  // [buf][32 x 64] bf16, swizzled
  __shared__ u16 Vs[2][2048];                  // [buf][64 x 32] bf16, swizzled

  const u16* Kg = K + (size_t)bh * S_LEN * DH;
  const u16* Vg = Vt + (size_t)bh * DH * S_LEN;

  // staging indices (tid-static)
  const int kr = tid >> 3, kcB = (tid & 7) << 4;
  const int vr = tid >> 2, vcB = (tid & 3) << 4;
  const int ksrcoff = ((kcB ^ ((kr & 7) << 4)) >> 1);
  const int vsrcoff = ((vcB ^ (((vr >> 1) & 3) << 4)) >> 1);

  // ---- Q fragments + static softmax bound ----
  const size_t qoff = ((size_t)bh * S_LEN + qbase + lr) * DH + lg * 8;
  const bf16x8 qA0 = *(const bf16x8*)(Q + qoff);
  const bf16x8 qA1 = *(const bf16x8*)(Q + qoff + 32);
  const bf16x8 qB0 = *(const bf16x8*)(Q + qoff + 16 * DH);
  const bf16x8 qB1 = *(const bf16x8*)(Q + qoff + 16 * DH + 32);

  float ssA = 0.f, ssB = 0.f;
#pragma unroll
  for (int j = 0; j < 8; j++) {
    float a0 = bf2f(qA0[j]), a1 = bf2f(qA1[j]);
    float b0 = bf2f(qB0[j]), b1 = bf2f(qB1[j]);
    ssA += a0 * a0 + a1 * a1;
    ssB += b0 * b0 + b1 * b1;
  }
  ssA += __shfl_xor(ssA, 16); ssA += __shfl_xor(ssA, 32);
  ssB += __shfl_xor(ssB, 16); ssB += __shfl_xor(ssB, 32);
  const float kmx = kmax[bh];
  const float mA = sqrtf(ssA) * kmx;
  const float mB = sqrtf(ssB) * kmx;

  f32x4 oA[4] = {}, oB[4] = {};
  float lA = 0.f, lB = 0.f;
  const f32x4 zero = {};

  // fragment read offsets (swizzled)
  const int kmsk = (lr & 7) << 4;
  const int k00 = lr * 64 + (((lg << 4)) ^ kmsk) / 2;
  const int k01 = lr * 64 + ((64 + (lg << 4)) ^ kmsk) / 2;
  const int k10 = (16 + lr) * 64 + (((lg << 4)) ^ kmsk) / 2;
  const int k11 = (16 + lr) * 64 + ((64 + (lg << 4)) ^ kmsk) / 2;
  const int vmsk = ((lr >> 1) & 3) << 4;
  const int vo = ((lg << 4) ^ vmsk) / 2;

  // ---- prologue: stage step 0 into buf 0 ----
  gload_lds16(Kg + (size_t)kr * DH + ksrcoff, &Ks[0][w << 9]);
  gload_lds16(Vg + (size_t)vr * S_LEN + vsrcoff, &Vs[0][w << 9]);

  for (int s = 0; s < nst; ++s) {
    const int b = s & 1;
    if (s + 1 < nst) {  // stage next step into the other buffer
      gload_lds16(Kg + (size_t)((s + 1) * 32 + kr) * DH + ksrcoff, &Ks[b ^ 1][w << 9]);
      gload_lds16(Vg + (size_t)vr * S_LEN + (s + 1) * 32 + vsrcoff, &Vs[b ^ 1][w << 9]);
    }
    __syncthreads();  // vmcnt(0) drain: buf b complete everywhere

    const u16* Kb = Ks[b];
    const u16* Vb = Vs[b];
    bf16x8 kc0 = *(const bf16x8*)&Kb[k00];
    bf16x8 kc1 = *(const bf16x8*)&Kb[k01];
    bf16x8 kc2 = *(const bf16x8*)&Kb[k10];
    bf16x8 kc3 = *(const bf16x8*)&Kb[k11];
    bf16x8 v0 = *(const bf16x8*)&Vb[(lr) * 32 + vo];
    bf16x8 v1 = *(const bf16x8*)&Vb[(16 + lr) * 32 + vo];
    bf16x8 v2 = *(const bf16x8*)&Vb[(32 + lr) * 32 + vo];
    bf16x8 v3 = *(const bf16x8*)&Vb[(48 + lr) * 32 + vo];

    f32x4 s0A = __builtin_amdgcn_mfma_f32_16x16x32_bf16(kc0, qA0, zero, 0, 0, 0);
    s0A = __builtin_amdgcn_mfma_f32_16x16x32_bf16(kc1, qA1, s0A, 0, 0, 0);
    f32x4 s1A = __builtin_amdgcn_mfma_f32_16x16x32_bf16(kc2, qA0, zero, 0, 0, 0);
    s1A = __builtin_amdgcn_mfma_f32_16x16x32_bf16(kc3, qA1, s1A, 0, 0, 0);
    f32x4 s0B = __builtin_amdgcn_mfma_f32_16x16x32_bf16(kc0, qB0, zero, 0, 0, 0);
    s0B = __builtin_amdgcn_mfma_f32_16x16x32_bf16(kc1, qB1, s0B, 0, 0, 0);
    f32x4 s1B = __builtin_amdgcn_mfma_f32_16x16x32_bf16(kc2, qB0, zero, 0, 0, 0);
    s1B = __builtin_amdgcn_mfma_f32_16x16x32_bf16(kc3, qB1, s1B, 0, 0, 0);

    // generic causal mask (passes automatically for steps below the diagonal)
    const int qrelA = qbase + lr - (s << 5) - (lg << 2);
    const int qrelB = qrelA + 16;
    float aA[8], aB[8];
#pragma unroll
    for (int r = 0; r < 4; r++) {
      aA[r]     = (r <= qrelA)      ? s0A[r] : -__builtin_inff();
      aA[4 + r] = (r + 16 <= qrelA) ? s1A[r] : -__builtin_inff();
      aB[r]     = (r <= qrelB)      ? s0B[r] : -__builtin_inff();
      aB[4 + r] = (r + 16 <= qrelB) ? s1B[r] : -__builtin_inff();
    }
    sm_pv(aA, mA, lA, v0, v1, v2, v3, oA);
    sm_pv(aB, mB, lB, v0, v1, v2, v3, oB);

    __syncthreads();  // all reads of buf b done before it is re-staged
  }

  // ---- epilogue: lane holds q=lr, d = dt*16 + lg*4 + r ----
  lA += __shfl_xor(lA, 16); lA += __shfl_xor(lA, 32);
  lB += __shfl_xor(lB, 16); lB += __shfl_xor(lB, 32);
  const float rlA = __builtin_amdgcn_rcpf(lA);
  const float rlB = __builtin_amdgcn_rcpf(lB);

  const int bb = bh >> 4, h = bh & 15;
  const size_t obaseA = ((size_t)bb * S_LEN + qbase + lr) * DM + h * DH;
  const size_t obaseB = obaseA + (size_t)16 * DM;
#pragma unroll
  for (int dt = 0; dt < 4; dt++) {
    u32x2 pkA, pkB;
    pkA.x = pkbf(oA[dt][0] * rlA, oA[dt][1] * rlA);
    pkA.y = pkbf(oA[dt][2] * rlA, oA[dt][3] * rlA);
    pkB.x = pkbf(oB[dt][0] * rlB, oB[dt][1] * rlB);
    pkB.y = pkbf(oB[dt][2] * rlB, oB[dt][3] * rlB);
    *(u32x2*)(Oo + obaseA + dt * 16 + lg * 4) = pkA;
    *(u32x2*)(Oo + obaseB + dt * 16 + lg * 4) = pkB;
  }
}

// ---------------- host launcher ----------------
extern "C" void kernel_launch(void* const* d_in, const int* in_sizes, int n_in,
                              void* d_out, int out_size, void* d_ws, size_t ws_size,
                              hipStream_t stream) {
  const float* x  = (const float*)d_in[0];
  const float* Wq = (const float*)d_in[1];
  const float* bq = (const float*)d_in[2];
  const float* Wk = (const float*)d_in[3];
  const float* bk = (const float*)d_in[4];
  const float* Wv = (const float*)d_in[5];
  const float* bv = (const float*)d_in[6];
  const float* Wo = (const float*)d_in[7];
  const float* bo = (const float*)d_in[8];

  char* ws = (char*)d_ws;
  u16* xb    = (u16*)(ws);                 // 8 MB  [4096,1024] bf16
  u16* wb    = (u16*)(ws + (8u << 20));    // 8 MB  Wq,Wk,Wv,Wo bf16
  u16* Qb    = (u16*)(ws + (16u << 20));   // 8 MB  [B,H,S,Dh]
  u16* Kb    = (u16*)(ws + (24u << 20));   // 8 MB  [B,H,S,Dh]
  u16* Vtb   = (u16*)(ws + (32u << 20));   // 8 MB  [B,H,Dh,S] (s-permuted)
  u16* AOb   = (u16*)(ws + (40u << 20));   // 8 MB  [B*S, DM]
  float2* rt = (float2*)(ws + (48u << 20));            // 512 KB rope table
  float* kmx = (float*)(ws + (48u << 20) + (512u << 10));  // 128 B kmax[32]

  convert_k<<<8192, 256, 0, stream>>>(x, Wq, Wk, Wv, Wo, xb, wb);
  rope_k<<<256, 256, 0, stream>>>(rt, kmx);
  gemm_k<<<768, 256, 0, stream>>>(xb, wb, wb + (1u << 20), wb + (2u << 20),
                                  bq, bk, bv, rt, Qb, Kb, Vtb, 0);
  knorm_k<<<256, 256, 0, stream>>>(Kb, kmx);
  attn_k<<<512, 256, 0, stream>>>(Qb, Kb, Vtb, AOb, kmx);
  gemm_k<<<256, 256, 0, stream>>>(AOb, wb + (3u << 20), wb + (3u << 20), wb + (3u << 20),
                                  bo, bo, bo, rt, d_out, d_out, d_out, 3);
}